// Round 1
// baseline (5317.757 us; speedup 1.0000x reference)
//
#include <hip/hip_runtime.h>

// ODE-RNN, fp32 correctness baseline.
// B=2048 trajectories, T=200 steps, D_lat=D_in=64, n_units=100.
// Grid: 256 blocks (1/CU) x 256 threads; each block owns NT=8 trajectories
// and loops the full 199-step scan (trajectories are independent -> no grid sync).
// Weights read from global (L2-resident, 282 KB); activations staged in LDS.

#define NBT   2048
#define TSTEP 200
#define DIN   64
#define DL    64
#define NU    100
#define NT    8     // trajectories per block
#define CPLX  (DL + DIN)   // concat width = 128

__device__ __forceinline__ float sigmoidf_(float x) {
    return 1.0f / (1.0f + __expf(-x));
}

// hidden layer: out[i][j] = tanh(b[j] + sum_k in[i][k] * W[k*NU+j]), j < NU
// mapping: j = tid & 127, g = tid >> 7; each active thread handles trajectories g*4 .. g*4+3
template <int K, int STR>
__device__ __forceinline__ void hidden_phase(const float (*in)[STR],
                                             const float* __restrict__ W,
                                             const float* __restrict__ bias,
                                             float (*outh)[NU],
                                             int j, int g) {
    if (j < NU) {
        const float b = bias[j];
        float a0 = b, a1 = b, a2 = b, a3 = b;
        const int i0 = g * 4;
#pragma unroll 4
        for (int k = 0; k < K; ++k) {
            const float w = W[k * NU + j];
            a0 = fmaf(in[i0 + 0][k], w, a0);
            a1 = fmaf(in[i0 + 1][k], w, a1);
            a2 = fmaf(in[i0 + 2][k], w, a2);
            a3 = fmaf(in[i0 + 3][k], w, a3);
        }
        outh[i0 + 0][j] = tanhf(a0);
        outh[i0 + 1][j] = tanhf(a1);
        outh[i0 + 2][j] = tanhf(a2);
        outh[i0 + 3][j] = tanhf(a3);
    }
}

// output layer pre-activation: a[i][j] = b[j] + sum_k h[i][k]*W[k*DL+j], j < 64
// mapping: j = tid & 63, q = tid >> 6; thread handles trajectories q*2, q*2+1
__device__ __forceinline__ void out_phase(const float (*h)[NU],
                                          const float* __restrict__ W,
                                          const float* __restrict__ bias,
                                          int j, int q,
                                          float& o0, float& o1) {
    const float b = bias[j];
    float a0 = b, a1 = b;
    const int i0 = q * 2;
#pragma unroll 4
    for (int k = 0; k < NU; ++k) {
        const float w = W[k * DL + j];
        a0 = fmaf(h[i0 + 0][k], w, a0);
        a1 = fmaf(h[i0 + 1][k], w, a1);
    }
    o0 = a0; o1 = a1;
}

__global__ __launch_bounds__(256) void ode_rnn_f32(
    const float* __restrict__ data, const float* __restrict__ tsv,
    const float* __restrict__ Wf1, const float* __restrict__ bf1,
    const float* __restrict__ Wf2, const float* __restrict__ bf2,
    const float* __restrict__ Wz1, const float* __restrict__ bz1,
    const float* __restrict__ Wz2, const float* __restrict__ bz2,
    const float* __restrict__ Wr1, const float* __restrict__ br1,
    const float* __restrict__ Wr2, const float* __restrict__ br2,
    const float* __restrict__ Wh1, const float* __restrict__ bh1,
    const float* __restrict__ Wh2, const float* __restrict__ bh2,
    float* __restrict__ out_yi, float* __restrict__ out_ys)
{
    __shared__ float s_y[NT][DL];       // current latent state
    __shared__ float s_c[NT][CPLX];     // concat [yode | x], later [yode*r | x]
    __shared__ float s_h[NT][NU];       // hidden activations (reused per MLP)
    __shared__ float s_yode[NT][DL];
    __shared__ float s_z[NT][DL];
    __shared__ float s_r[NT][DL];

    const int tid = threadIdx.x;
    const int b0  = blockIdx.x * NT;

    // init y = 0
    for (int e = tid; e < NT * DL; e += 256) ((float*)s_y)[e] = 0.0f;
    __syncthreads();

    const int j128 = tid & 127, g = tid >> 7;   // hidden-phase mapping
    const int j64  = tid & 63,  q = tid >> 6;   // output-phase mapping
    const int i0   = q * 2, i1 = q * 2 + 1;

    for (int s = 0; s < TSTEP - 1; ++s) {
        // faithful dt sequence: s==0 -> ts[1]-ts[0]; s>=1 -> ts[s-1]-ts[s]
        const float dt = (s == 0) ? (tsv[1] - tsv[0]) : (tsv[s - 1] - tsv[s]);

        // ---- phase 1: ODE-func hidden: tanh(y @ Wf1 + bf1) ----
        hidden_phase<DL, DL>(s_y, Wf1, bf1, s_h, j128, g);
        __syncthreads();

        // ---- phase 2: yode = y + dt * (h @ Wf2 + bf2); build c = [yode | x] ----
        {
            float a0, a1;
            out_phase(s_h, Wf2, bf2, j64, q, a0, a1);
            const float y0 = fmaf(dt, a0, s_y[i0][j64]);
            const float y1 = fmaf(dt, a1, s_y[i1][j64]);
            s_yode[i0][j64] = y0;  s_c[i0][j64] = y0;
            s_yode[i1][j64] = y1;  s_c[i1][j64] = y1;
            // x = data[:, s+1, :]
            s_c[i0][DL + j64] = data[((size_t)(b0 + i0) * TSTEP + (s + 1)) * DIN + j64];
            s_c[i1][DL + j64] = data[((size_t)(b0 + i1) * TSTEP + (s + 1)) * DIN + j64];
        }
        __syncthreads();

        // ---- phase 3/4: z = sigmoid(mlp_z(c)) ----
        hidden_phase<CPLX, CPLX>(s_c, Wz1, bz1, s_h, j128, g);
        __syncthreads();
        {
            float a0, a1;
            out_phase(s_h, Wz2, bz2, j64, q, a0, a1);
            s_z[i0][j64] = sigmoidf_(a0);
            s_z[i1][j64] = sigmoidf_(a1);
        }
        __syncthreads();

        // ---- phase 5/6: r = sigmoid(mlp_r(c)) ----
        hidden_phase<CPLX, CPLX>(s_c, Wr1, br1, s_h, j128, g);
        __syncthreads();
        {
            float a0, a1;
            out_phase(s_h, Wr2, br2, j64, q, a0, a1);
            s_r[i0][j64] = sigmoidf_(a0);
            s_r[i1][j64] = sigmoidf_(a1);
        }
        __syncthreads();

        // ---- phase 7: ch = [yode * r | x] (overwrite first half of c) ----
        s_c[i0][j64] = s_yode[i0][j64] * s_r[i0][j64];
        s_c[i1][j64] = s_yode[i1][j64] * s_r[i1][j64];
        __syncthreads();

        // ---- phase 8/9: h = tanh(mlp_h(ch)); y = (1-z)*h + z*yode ----
        hidden_phase<CPLX, CPLX>(s_c, Wh1, bh1, s_h, j128, g);
        __syncthreads();
        {
            float a0, a1;
            out_phase(s_h, Wh2, bh2, j64, q, a0, a1);
            const float h0 = tanhf(a0), h1 = tanhf(a1);
            const float z0 = s_z[i0][j64], z1 = s_z[i1][j64];
            const float y0 = (1.0f - z0) * h0 + z0 * s_yode[i0][j64];
            const float y1 = (1.0f - z1) * h1 + z1 * s_yode[i1][j64];
            s_y[i0][j64] = y0;
            s_y[i1][j64] = y1;
            out_ys[((size_t)(b0 + i0) * (TSTEP - 1) + s) * DL + j64] = y0;
            out_ys[((size_t)(b0 + i1) * (TSTEP - 1) + s) * DL + j64] = y1;
            if (s == TSTEP - 2) {
                out_yi[(size_t)(b0 + i0) * DL + j64] = y0;
                out_yi[(size_t)(b0 + i1) * DL + j64] = y1;
            }
        }
        __syncthreads();
    }
}

extern "C" void kernel_launch(void* const* d_in, const int* in_sizes, int n_in,
                              void* d_out, int out_size, void* d_ws, size_t ws_size,
                              hipStream_t stream) {
    const float* data = (const float*)d_in[0];
    const float* tsv  = (const float*)d_in[1];
    const float* Wf1 = (const float*)d_in[2];  const float* bf1 = (const float*)d_in[3];
    const float* Wf2 = (const float*)d_in[4];  const float* bf2 = (const float*)d_in[5];
    const float* Wz1 = (const float*)d_in[6];  const float* bz1 = (const float*)d_in[7];
    const float* Wz2 = (const float*)d_in[8];  const float* bz2 = (const float*)d_in[9];
    const float* Wr1 = (const float*)d_in[10]; const float* br1 = (const float*)d_in[11];
    const float* Wr2 = (const float*)d_in[12]; const float* br2 = (const float*)d_in[13];
    const float* Wh1 = (const float*)d_in[14]; const float* bh1 = (const float*)d_in[15];
    const float* Wh2 = (const float*)d_in[16]; const float* bh2 = (const float*)d_in[17];

    float* out_yi = (float*)d_out;                 // [B, 64]
    float* out_ys = out_yi + (size_t)NBT * DL;     // [B, T-1, 64]

    ode_rnn_f32<<<NBT / NT, 256, 0, stream>>>(
        data, tsv, Wf1, bf1, Wf2, bf2, Wz1, bz1, Wz2, bz2,
        Wr1, br1, Wr2, br2, Wh1, bh1, Wh2, bh2, out_yi, out_ys);
}

// Round 2
// 3370.182 us; speedup vs baseline: 1.5779x; 1.5779x over previous
//
#include <hip/hip_runtime.h>

// ODE-RNN: all weights staged once per block into LDS as bf16, transposed
// (column-major Wt[j][k]) with XOR bank swizzle; fp32 activations/accum.
// 256 blocks (1/CU) x 256 threads; NT=8 trajectories/block; 199-step loop.

#define NBT   2048
#define TSTEP 200
#define NT    8

// LDS layout (bytes)
#define OFF_WF1T 0        // 100 rows x 128 B (K=64 bf16)
#define OFF_WZ1T 12800    // 100 rows x 256 B (K=128 bf16)
#define OFF_WR1T 38400
#define OFF_WH1T 64000
#define OFF_WF2T 89600    // 64 rows x 256 B (K padded 100->128 bf16, zero pad)
#define OFF_WZ2T 105984
#define OFF_WR2T 122368
#define OFF_WH2T 138752
#define OFF_SC   155136   // f32 [8][128]  (cols 0..63 = y/yode/yode*r, 64..127 = x)
#define OFF_SH   159232   // f32 [8][104]  (k pad 100->104, zero pad)
#define SMEM_BYTES 162560

__device__ __forceinline__ float blo(unsigned int u) { return __uint_as_float(u << 16); }
__device__ __forceinline__ float bhi(unsigned int u) { return __uint_as_float(u & 0xffff0000u); }

__device__ __forceinline__ float tanh_f(float x) {
    float e = __expf(2.0f * x);
    return fmaf(-2.0f, __builtin_amdgcn_rcpf(e + 1.0f), 1.0f);
}
__device__ __forceinline__ float sigm_f(float x) {
    return __builtin_amdgcn_rcpf(1.0f + __expf(-x));
}

__device__ __forceinline__ unsigned short f2bf(float f) {
    unsigned int b = __float_as_uint(f);
    return (unsigned short)((b + 0x7fffu + ((b >> 16) & 1u)) >> 16);
}

// stage W[K][100] (row-major fp32) -> dst rows j<100, row stride RB bytes,
// elem (j,k) at byte j*RB + ((k*2) ^ ((j&7)<<4))   (bf16)
__device__ void stage_w1(const float* __restrict__ W, char* __restrict__ dst,
                         int K, int RB, int tid) {
    const int total = K * 100;
    for (int idx = tid; idx < total; idx += 256) {
        const int k = idx / 100;
        const int j = idx - k * 100;
        *(unsigned short*)(dst + j * RB + ((k * 2) ^ ((j & 7) << 4))) = f2bf(W[idx]);
    }
}

// stage W[100][64] -> dst rows j<64, 256B rows, same swizzle (pad region pre-zeroed)
__device__ void stage_w2(const float* __restrict__ W, char* __restrict__ dst, int tid) {
    for (int idx = tid; idx < 6400; idx += 256) {
        const int j = idx & 63;
        const int k = idx >> 6;
        *(unsigned short*)(dst + j * 256 + ((k * 2) ^ ((j & 7) << 4))) = f2bf(W[idx]);
    }
}

// hidden layer: lane j computes tanh(bias + sum_k in[t][k]*W[k][j]) for 4 trajs
template <int NCH, int RB>
__device__ __forceinline__ void hidden_mlp(const char* __restrict__ Wt,
                                           const float* __restrict__ sc,
                                           int t0, float bias, int j,
                                           float* __restrict__ sh) {
    float a0 = bias, a1 = bias, a2 = bias, a3 = bias;
    const char* wrow = Wt + j * RB;
    const int swz = (j & 7) << 4;
    const float* r0 = sc + (t0 + 0) * 128;
    const float* r1 = sc + (t0 + 1) * 128;
    const float* r2 = sc + (t0 + 2) * 128;
    const float* r3 = sc + (t0 + 3) * 128;
#pragma unroll
    for (int kc = 0; kc < NCH; ++kc) {
        const uint4 w = *(const uint4*)(wrow + ((kc * 16) ^ swz));
        const float w0 = blo(w.x), w1 = bhi(w.x), w2 = blo(w.y), w3 = bhi(w.y);
        const float w4 = blo(w.z), w5 = bhi(w.z), w6 = blo(w.w), w7 = bhi(w.w);
        float4 p, q;
        p = *(const float4*)(r0 + kc * 8); q = *(const float4*)(r0 + kc * 8 + 4);
        a0 = fmaf(p.x, w0, a0); a0 = fmaf(p.y, w1, a0); a0 = fmaf(p.z, w2, a0); a0 = fmaf(p.w, w3, a0);
        a0 = fmaf(q.x, w4, a0); a0 = fmaf(q.y, w5, a0); a0 = fmaf(q.z, w6, a0); a0 = fmaf(q.w, w7, a0);
        p = *(const float4*)(r1 + kc * 8); q = *(const float4*)(r1 + kc * 8 + 4);
        a1 = fmaf(p.x, w0, a1); a1 = fmaf(p.y, w1, a1); a1 = fmaf(p.z, w2, a1); a1 = fmaf(p.w, w3, a1);
        a1 = fmaf(q.x, w4, a1); a1 = fmaf(q.y, w5, a1); a1 = fmaf(q.z, w6, a1); a1 = fmaf(q.w, w7, a1);
        p = *(const float4*)(r2 + kc * 8); q = *(const float4*)(r2 + kc * 8 + 4);
        a2 = fmaf(p.x, w0, a2); a2 = fmaf(p.y, w1, a2); a2 = fmaf(p.z, w2, a2); a2 = fmaf(p.w, w3, a2);
        a2 = fmaf(q.x, w4, a2); a2 = fmaf(q.y, w5, a2); a2 = fmaf(q.z, w6, a2); a2 = fmaf(q.w, w7, a2);
        p = *(const float4*)(r3 + kc * 8); q = *(const float4*)(r3 + kc * 8 + 4);
        a3 = fmaf(p.x, w0, a3); a3 = fmaf(p.y, w1, a3); a3 = fmaf(p.z, w2, a3); a3 = fmaf(p.w, w3, a3);
        a3 = fmaf(q.x, w4, a3); a3 = fmaf(q.y, w5, a3); a3 = fmaf(q.z, w6, a3); a3 = fmaf(q.w, w7, a3);
    }
    sh[(t0 + 0) * 104 + j] = tanh_f(a0);
    sh[(t0 + 1) * 104 + j] = tanh_f(a1);
    sh[(t0 + 2) * 104 + j] = tanh_f(a2);
    sh[(t0 + 3) * 104 + j] = tanh_f(a3);
}

// output layer pre-activation for 2 trajs: lane = output j
__device__ __forceinline__ void out_mlp(const char* __restrict__ Wt,
                                        const float* __restrict__ sh,
                                        int p0, float bias, int lane,
                                        float& o0, float& o1) {
    float a0 = bias, a1 = bias;
    const char* wrow = Wt + lane * 256;
    const int swz = (lane & 7) << 4;
    const float* h0 = sh + p0 * 104;
    const float* h1 = h0 + 104;
#pragma unroll
    for (int kc = 0; kc < 13; ++kc) {
        const uint4 w = *(const uint4*)(wrow + ((kc * 16) ^ swz));
        const float w0 = blo(w.x), w1 = bhi(w.x), w2 = blo(w.y), w3 = bhi(w.y);
        const float w4 = blo(w.z), w5 = bhi(w.z), w6 = blo(w.w), w7 = bhi(w.w);
        float4 p, q;
        p = *(const float4*)(h0 + kc * 8); q = *(const float4*)(h0 + kc * 8 + 4);
        a0 = fmaf(p.x, w0, a0); a0 = fmaf(p.y, w1, a0); a0 = fmaf(p.z, w2, a0); a0 = fmaf(p.w, w3, a0);
        a0 = fmaf(q.x, w4, a0); a0 = fmaf(q.y, w5, a0); a0 = fmaf(q.z, w6, a0); a0 = fmaf(q.w, w7, a0);
        p = *(const float4*)(h1 + kc * 8); q = *(const float4*)(h1 + kc * 8 + 4);
        a1 = fmaf(p.x, w0, a1); a1 = fmaf(p.y, w1, a1); a1 = fmaf(p.z, w2, a1); a1 = fmaf(p.w, w3, a1);
        a1 = fmaf(q.x, w4, a1); a1 = fmaf(q.y, w5, a1); a1 = fmaf(q.z, w6, a1); a1 = fmaf(q.w, w7, a1);
    }
    o0 = a0; o1 = a1;
}

__global__ __launch_bounds__(256) void ode_rnn_lds(
    const float* __restrict__ data, const float* __restrict__ tsv,
    const float* __restrict__ Wf1, const float* __restrict__ bf1,
    const float* __restrict__ Wf2, const float* __restrict__ bf2,
    const float* __restrict__ Wz1, const float* __restrict__ bz1,
    const float* __restrict__ Wz2, const float* __restrict__ bz2,
    const float* __restrict__ Wr1, const float* __restrict__ br1,
    const float* __restrict__ Wr2, const float* __restrict__ br2,
    const float* __restrict__ Wh1, const float* __restrict__ bh1,
    const float* __restrict__ Wh2, const float* __restrict__ bh2,
    float* __restrict__ out_yi, float* __restrict__ out_ys)
{
    extern __shared__ char smem[];
    float* s_c = (float*)(smem + OFF_SC);
    float* s_h = (float*)(smem + OFF_SH);

    const int tid  = threadIdx.x;
    const int lane = tid & 63;
    const int wv   = tid >> 6;
    const int b0   = blockIdx.x * NT;

    // zero W2 region (for k-pad) and s_c + s_h (y init + k-pad)
    for (int i = tid; i < 16384; i += 256) ((unsigned int*)(smem + OFF_WF2T))[i] = 0u;
    for (int i = tid; i < 1856;  i += 256) ((unsigned int*)(smem + OFF_SC))[i]   = 0u;
    __syncthreads();

    stage_w1(Wf1, smem + OFF_WF1T,  64, 128, tid);
    stage_w1(Wz1, smem + OFF_WZ1T, 128, 256, tid);
    stage_w1(Wr1, smem + OFF_WR1T, 128, 256, tid);
    stage_w1(Wh1, smem + OFF_WH1T, 128, 256, tid);
    stage_w2(Wf2, smem + OFF_WF2T, tid);
    stage_w2(Wz2, smem + OFF_WZ2T, tid);
    stage_w2(Wr2, smem + OFF_WR2T, tid);
    stage_w2(Wh2, smem + OFF_WH2T, tid);
    __syncthreads();

    // hidden-phase mapping: j = (wv&1)*64 + lane over 2 wave-pairs of 4 trajs
    const int jh  = (wv & 1) * 64 + lane;
    const int t0  = (wv >> 1) * 4;
    const bool hok = (jh < 100);
    // out-phase mapping: lane = output j, wave handles trajs p0, p0+1
    const int p0 = wv * 2;

    const float bjf1 = hok ? bf1[jh] : 0.0f;
    const float bjz1 = hok ? bz1[jh] : 0.0f;
    const float bjr1 = hok ? br1[jh] : 0.0f;
    const float bjh1 = hok ? bh1[jh] : 0.0f;
    const float blf2 = bf2[lane], blz2 = bz2[lane], blr2 = br2[lane], blh2 = bh2[lane];

    for (int s = 0; s < TSTEP - 1; ++s) {
        // prefetch x = data[:, s+1, :] (hidden under phase 1)
        const float x0 = data[((size_t)(b0 + p0) * TSTEP + (s + 1)) * 64 + lane];
        const float x1 = data[((size_t)(b0 + p0 + 1) * TSTEP + (s + 1)) * 64 + lane];
        const float dt = (s == 0) ? (tsv[1] - tsv[0]) : (tsv[s - 1] - tsv[s]);

        // P1: f1 hidden (reads s_c[:, :64] = y)
        if (hok) hidden_mlp<8, 128>(smem + OFF_WF1T, s_c, t0, bjf1, jh, s_h);
        __syncthreads();

        // P2: f2 out -> yode; write c = [yode | x]
        float o0, o1;
        const float y0s = s_c[p0 * 128 + lane];
        const float y1s = s_c[(p0 + 1) * 128 + lane];
        out_mlp(smem + OFF_WF2T, s_h, p0, blf2, lane, o0, o1);
        const float yo0 = fmaf(dt, o0, y0s);
        const float yo1 = fmaf(dt, o1, y1s);
        s_c[p0 * 128 + lane] = yo0;       s_c[p0 * 128 + 64 + lane] = x0;
        s_c[(p0 + 1) * 128 + lane] = yo1; s_c[(p0 + 1) * 128 + 64 + lane] = x1;
        __syncthreads();

        // P3: z hidden
        if (hok) hidden_mlp<16, 256>(smem + OFF_WZ1T, s_c, t0, bjz1, jh, s_h);
        __syncthreads();

        // P4: z out
        out_mlp(smem + OFF_WZ2T, s_h, p0, blz2, lane, o0, o1);
        const float z0 = sigm_f(o0), z1 = sigm_f(o1);
        __syncthreads();

        // P5: r hidden
        if (hok) hidden_mlp<16, 256>(smem + OFF_WR1T, s_c, t0, bjr1, jh, s_h);
        __syncthreads();

        // P6: r out; write c[:, :64] = yode * r
        out_mlp(smem + OFF_WR2T, s_h, p0, blr2, lane, o0, o1);
        s_c[p0 * 128 + lane] = yo0 * sigm_f(o0);
        s_c[(p0 + 1) * 128 + lane] = yo1 * sigm_f(o1);
        __syncthreads();

        // P7: h hidden
        if (hok) hidden_mlp<16, 256>(smem + OFF_WH1T, s_c, t0, bjh1, jh, s_h);
        __syncthreads();

        // P8: h out; y = (1-z)*h + z*yode; write back + store
        out_mlp(smem + OFF_WH2T, s_h, p0, blh2, lane, o0, o1);
        {
            const float h0 = tanh_f(o0), h1 = tanh_f(o1);
            const float yn0 = (1.0f - z0) * h0 + z0 * yo0;
            const float yn1 = (1.0f - z1) * h1 + z1 * yo1;
            s_c[p0 * 128 + lane] = yn0;
            s_c[(p0 + 1) * 128 + lane] = yn1;
            out_ys[((size_t)(b0 + p0) * (TSTEP - 1) + s) * 64 + lane] = yn0;
            out_ys[((size_t)(b0 + p0 + 1) * (TSTEP - 1) + s) * 64 + lane] = yn1;
            if (s == TSTEP - 2) {
                out_yi[(size_t)(b0 + p0) * 64 + lane] = yn0;
                out_yi[(size_t)(b0 + p0 + 1) * 64 + lane] = yn1;
            }
        }
        __syncthreads();
    }
}

extern "C" void kernel_launch(void* const* d_in, const int* in_sizes, int n_in,
                              void* d_out, int out_size, void* d_ws, size_t ws_size,
                              hipStream_t stream) {
    const float* data = (const float*)d_in[0];
    const float* tsv  = (const float*)d_in[1];
    const float* Wf1 = (const float*)d_in[2];  const float* bf1 = (const float*)d_in[3];
    const float* Wf2 = (const float*)d_in[4];  const float* bf2 = (const float*)d_in[5];
    const float* Wz1 = (const float*)d_in[6];  const float* bz1 = (const float*)d_in[7];
    const float* Wz2 = (const float*)d_in[8];  const float* bz2 = (const float*)d_in[9];
    const float* Wr1 = (const float*)d_in[10]; const float* br1 = (const float*)d_in[11];
    const float* Wr2 = (const float*)d_in[12]; const float* br2 = (const float*)d_in[13];
    const float* Wh1 = (const float*)d_in[14]; const float* bh1 = (const float*)d_in[15];
    const float* Wh2 = (const float*)d_in[16]; const float* bh2 = (const float*)d_in[17];

    float* out_yi = (float*)d_out;
    float* out_ys = out_yi + (size_t)NBT * 64;

    (void)hipFuncSetAttribute((const void*)ode_rnn_lds,
                              hipFuncAttributeMaxDynamicSharedMemorySize, SMEM_BYTES);

    ode_rnn_lds<<<NBT / NT, 256, SMEM_BYTES, stream>>>(
        data, tsv, Wf1, bf1, Wf2, bf2, Wz1, bz1, Wz2, bz2,
        Wr1, br1, Wr2, br2, Wh1, bh1, Wh2, bh2, out_yi, out_ys);
}

// Round 4
// 420.400 us; speedup vs baseline: 12.6493x; 8.0166x over previous
//
#include <hip/hip_runtime.h>

// ODE-RNN via MFMA: weights live in VGPRs as pre-staged B-fragments (bf16),
// activations round-trip LDS as bf16 [16][K] tiles, GRU state in fp32 regs.
// 256 blocks (1/CU) x 256 threads (4 waves); NT=8 trajs (M=8 of 16 used).
// Wave w owns N-tiles {w, w+4} of W1 layers (units padded 100->128) and
// N-tile w of W2 layers (latent 64 = 4 tiles).
// Fragment mapping (16x16x32 bf16): A: lane l -> A[l&15][kt*32+(l>>4)*8+j],
// B: lane l -> B[kt*32+(l>>4)*8+j][l&15], C/D: col=l&15, row=(l>>4)*4+reg.

#define NBT   2048
#define TSTEP 200
#define NT    8

typedef short s8v __attribute__((ext_vector_type(8)));   // 8 bf16 (4 VGPRs)
typedef float f4v __attribute__((ext_vector_type(4)));

// LDS: bf16 activation tiles, row pitch chosen so (pitch/4)%32 == 4
// -> row-base bank = 4r mod 32 -> worst 2-way conflict (free), 16B aligned.
#define RB_Y 144   // y  [16][64]  bf16 (+pad)
#define RB_C 272   // c  [16][128] bf16 (+pad); also pitch for h buffers
#define OFF_Y  0
#define OFF_C  2304
#define OFF_HF 6656
#define OFF_HZ 11008
#define OFF_HR 15360
#define OFF_HH 19712
#define SMEM_TOT 24064

__device__ __forceinline__ unsigned short f2bf(float f) {
    unsigned int b = __float_as_uint(f);
    return (unsigned short)((b + 0x7fffu + ((b >> 16) & 1u)) >> 16);
}
__device__ __forceinline__ float tanh_f(float x) {
    float e = __expf(2.0f * x);
    return fmaf(-2.0f, __builtin_amdgcn_rcpf(e + 1.0f), 1.0f);
}
__device__ __forceinline__ float sigm_f(float x) {
    return __builtin_amdgcn_rcpf(1.0f + __expf(-x));
}

__device__ __forceinline__ f4v mfma16(s8v a, s8v b, f4v c) {
    return __builtin_amdgcn_mfma_f32_16x16x32_bf16(a, b, c, 0, 0, 0);
}

// B-fragment: lane holds W[k0+j][n] j=0..7 (k0 includes (lane>>4)*8), bf16.
__device__ __forceinline__ s8v load_bfrag(const float* __restrict__ W,
                                          int Ncols, int Krows, int k0, int n) {
    s8v r;
#pragma unroll
    for (int j = 0; j < 8; ++j) {
        const int k = k0 + j;
        const float v = (k < Krows && n < Ncols) ? W[k * Ncols + n] : 0.0f;
        r[j] = (short)f2bf(v);
    }
    return r;
}

// A-fragment read: lane l -> act[l&15][kt*32 + (l>>4)*8 .. +7]
// byte offset within row: kt*64 + (l>>4)*16   (16B aligned)
template <int RB>
__device__ __forceinline__ s8v load_af(const char* base, int lane, int kt) {
    return *(const s8v*)(base + (lane & 15) * RB + ((lane >> 4) * 16) + kt * 64);
}

// store 4 accumulator rows (tanh-activated) as bf16 into tile col n0+(l&15)
__device__ __forceinline__ void store_tanh(char* base, int n0, int lane, f4v a) {
#pragma unroll
    for (int r = 0; r < 4; ++r) {
        const int row = (lane >> 4) * 4 + r;
        *(short*)(base + row * RB_C + (n0 + (lane & 15)) * 2) =
            f2bf(tanh_f(a[r]));
    }
}

__device__ __forceinline__ f4v splat(float b) { f4v v = {b, b, b, b}; return v; }

__global__ __launch_bounds__(256, 1) void ode_rnn_mfma(
    const float* __restrict__ data, const float* __restrict__ tsv,
    const float* __restrict__ Wf1, const float* __restrict__ bf1,
    const float* __restrict__ Wf2, const float* __restrict__ bf2,
    const float* __restrict__ Wz1, const float* __restrict__ bz1,
    const float* __restrict__ Wz2, const float* __restrict__ bz2,
    const float* __restrict__ Wr1, const float* __restrict__ br1,
    const float* __restrict__ Wr2, const float* __restrict__ br2,
    const float* __restrict__ Wh1, const float* __restrict__ bh1,
    const float* __restrict__ Wh2, const float* __restrict__ bh2,
    float* __restrict__ out_yi, float* __restrict__ out_ys)
{
    __shared__ __align__(16) char smem[SMEM_TOT];

    const int tid  = threadIdx.x;
    const int lane = tid & 63;
    const int wv   = tid >> 6;
    const int b0   = blockIdx.x * NT;

    // zero all activation LDS (y=0 init; pad rows/cols stay 0)
    for (int i = tid; i < SMEM_TOT / 4; i += 256) ((unsigned*)smem)[i] = 0u;

    // ---- stage weight B-fragments into VGPRs (once) ----
    const int kb  = (lane >> 4) * 8;
    const int nA  = wv * 16 + (lane & 15);         // W1 tile wv
    const int nB  = (wv + 4) * 16 + (lane & 15);   // W1 tile wv+4
    const int n2  = wv * 16 + (lane & 15);         // W2 tile wv (<64)

    s8v Bf1[2][2], Bz1[2][4], Br1[2][4], Bh1[2][4];
    s8v Bf2[4], Bz2[4], Br2[4], Bh2[4];
#pragma unroll
    for (int kt = 0; kt < 2; ++kt) {
        Bf1[0][kt] = load_bfrag(Wf1, 100, 64, kt * 32 + kb, nA);
        Bf1[1][kt] = load_bfrag(Wf1, 100, 64, kt * 32 + kb, nB);
    }
#pragma unroll
    for (int kt = 0; kt < 4; ++kt) {
        Bz1[0][kt] = load_bfrag(Wz1, 100, 128, kt * 32 + kb, nA);
        Bz1[1][kt] = load_bfrag(Wz1, 100, 128, kt * 32 + kb, nB);
        Br1[0][kt] = load_bfrag(Wr1, 100, 128, kt * 32 + kb, nA);
        Br1[1][kt] = load_bfrag(Wr1, 100, 128, kt * 32 + kb, nB);
        Bh1[0][kt] = load_bfrag(Wh1, 100, 128, kt * 32 + kb, nA);
        Bh1[1][kt] = load_bfrag(Wh1, 100, 128, kt * 32 + kb, nB);
        Bf2[kt] = load_bfrag(Wf2, 64, 100, kt * 32 + kb, n2);
        Bz2[kt] = load_bfrag(Wz2, 64, 100, kt * 32 + kb, n2);
        Br2[kt] = load_bfrag(Wr2, 64, 100, kt * 32 + kb, n2);
        Bh2[kt] = load_bfrag(Wh2, 64, 100, kt * 32 + kb, n2);
    }

    const float bf1A = (nA < 100) ? bf1[nA] : 0.0f;
    const float bf1B = (nB < 100) ? bf1[nB] : 0.0f;
    const float bz1A = (nA < 100) ? bz1[nA] : 0.0f;
    const float bz1B = (nB < 100) ? bz1[nB] : 0.0f;
    const float br1A = (nA < 100) ? br1[nA] : 0.0f;
    const float br1B = (nB < 100) ? br1[nB] : 0.0f;
    const float bh1A = (nA < 100) ? bh1[nA] : 0.0f;
    const float bh1B = (nB < 100) ? bh1[nB] : 0.0f;
    const float bF2 = bf2[n2], bZ2 = bz2[n2], bR2 = br2[n2], bH2 = bh2[n2];

    // x-staging mapping: thread -> (traj, 2 elems)
    const int xtr = tid >> 5;
    const int xd  = (tid & 31) * 2;

    f4v y_reg = splat(0.0f);   // wave wv owns latent cols 16wv..16wv+15, 4 rows
    __syncthreads();

    for (int s = 0; s < TSTEP - 1; ++s) {
        // prefetch x = data[:, s+1, :]
        const float2 xv = *(const float2*)
            &data[((size_t)(b0 + xtr) * TSTEP + (s + 1)) * 64 + xd];
        const float dt = (s == 0) ? (tsv[1] - tsv[0]) : (tsv[s - 1] - tsv[s]);

        // ---- P1: f1 hidden: tanh(y @ Wf1 + b) -> h_f ----
        {
            const s8v ya0 = load_af<RB_Y>(smem + OFF_Y, lane, 0);
            const s8v ya1 = load_af<RB_Y>(smem + OFF_Y, lane, 1);
            f4v aA = splat(bf1A), aB = splat(bf1B);
            aA = mfma16(ya0, Bf1[0][0], aA); aA = mfma16(ya1, Bf1[0][1], aA);
            aB = mfma16(ya0, Bf1[1][0], aB); aB = mfma16(ya1, Bf1[1][1], aB);
            store_tanh(smem + OFF_HF, wv * 16, lane, aA);
            store_tanh(smem + OFF_HF, (wv + 4) * 16, lane, aB);
        }
        __syncthreads();

        // ---- P2: f2 out -> yode; write [yode | x] into c ----
        f4v yode;
        {
            f4v ac = splat(bF2);
#pragma unroll
            for (int kt = 0; kt < 4; ++kt)
                ac = mfma16(load_af<RB_C>(smem + OFF_HF, lane, kt), Bf2[kt], ac);
#pragma unroll
            for (int r = 0; r < 4; ++r) yode[r] = fmaf(dt, ac[r], y_reg[r]);
#pragma unroll
            for (int r = 0; r < 4; ++r) {
                const int row = (lane >> 4) * 4 + r;
                *(short*)(smem + OFF_C + row * RB_C + n2 * 2) = f2bf(yode[r]);
            }
            const unsigned xp = (unsigned)f2bf(xv.x) | ((unsigned)f2bf(xv.y) << 16);
            *(unsigned*)(smem + OFF_C + xtr * RB_C + 128 + (tid & 31) * 4) = xp;
        }
        __syncthreads();

        // ---- P3: z1 + r1 hidden from c ----
        {
            s8v c0 = load_af<RB_C>(smem + OFF_C, lane, 0);
            s8v c1 = load_af<RB_C>(smem + OFF_C, lane, 1);
            s8v c2 = load_af<RB_C>(smem + OFF_C, lane, 2);
            s8v c3 = load_af<RB_C>(smem + OFF_C, lane, 3);
            f4v az0 = splat(bz1A), az1 = splat(bz1B);
            f4v ar0 = splat(br1A), ar1 = splat(br1B);
            az0 = mfma16(c0, Bz1[0][0], az0); az0 = mfma16(c1, Bz1[0][1], az0);
            az0 = mfma16(c2, Bz1[0][2], az0); az0 = mfma16(c3, Bz1[0][3], az0);
            az1 = mfma16(c0, Bz1[1][0], az1); az1 = mfma16(c1, Bz1[1][1], az1);
            az1 = mfma16(c2, Bz1[1][2], az1); az1 = mfma16(c3, Bz1[1][3], az1);
            ar0 = mfma16(c0, Br1[0][0], ar0); ar0 = mfma16(c1, Br1[0][1], ar0);
            ar0 = mfma16(c2, Br1[0][2], ar0); ar0 = mfma16(c3, Br1[0][3], ar0);
            ar1 = mfma16(c0, Br1[1][0], ar1); ar1 = mfma16(c1, Br1[1][1], ar1);
            ar1 = mfma16(c2, Br1[1][2], ar1); ar1 = mfma16(c3, Br1[1][3], ar1);
            store_tanh(smem + OFF_HZ, wv * 16, lane, az0);
            store_tanh(smem + OFF_HZ, (wv + 4) * 16, lane, az1);
            store_tanh(smem + OFF_HR, wv * 16, lane, ar0);
            store_tanh(smem + OFF_HR, (wv + 4) * 16, lane, ar1);
        }
        __syncthreads();

        // ---- P4: z2, r2 out; z in regs; write ch = yode*r into c[:, :64] ----
        f4v zf;
        {
            f4v az = splat(bZ2), ar = splat(bR2);
#pragma unroll
            for (int kt = 0; kt < 4; ++kt) {
                az = mfma16(load_af<RB_C>(smem + OFF_HZ, lane, kt), Bz2[kt], az);
                ar = mfma16(load_af<RB_C>(smem + OFF_HR, lane, kt), Br2[kt], ar);
            }
#pragma unroll
            for (int r = 0; r < 4; ++r) {
                zf[r] = sigm_f(az[r]);
                const float rr = sigm_f(ar[r]);
                const int row = (lane >> 4) * 4 + r;
                *(short*)(smem + OFF_C + row * RB_C + n2 * 2) =
                    f2bf(yode[r] * rr);
            }
        }
        __syncthreads();

        // ---- P5: h1 hidden from [ch | x] ----
        {
            s8v d0 = load_af<RB_C>(smem + OFF_C, lane, 0);
            s8v d1 = load_af<RB_C>(smem + OFF_C, lane, 1);
            s8v d2 = load_af<RB_C>(smem + OFF_C, lane, 2);
            s8v d3 = load_af<RB_C>(smem + OFF_C, lane, 3);
            f4v ah0 = splat(bh1A), ah1 = splat(bh1B);
            ah0 = mfma16(d0, Bh1[0][0], ah0); ah0 = mfma16(d1, Bh1[0][1], ah0);
            ah0 = mfma16(d2, Bh1[0][2], ah0); ah0 = mfma16(d3, Bh1[0][3], ah0);
            ah1 = mfma16(d0, Bh1[1][0], ah1); ah1 = mfma16(d1, Bh1[1][1], ah1);
            ah1 = mfma16(d2, Bh1[1][2], ah1); ah1 = mfma16(d3, Bh1[1][3], ah1);
            store_tanh(smem + OFF_HH, wv * 16, lane, ah0);
            store_tanh(smem + OFF_HH, (wv + 4) * 16, lane, ah1);
        }
        __syncthreads();

        // ---- P6: h2 out; y = (1-z)*h + z*yode; write y LDS + global ----
        {
            f4v ah = splat(bH2);
#pragma unroll
            for (int kt = 0; kt < 4; ++kt)
                ah = mfma16(load_af<RB_C>(smem + OFF_HH, lane, kt), Bh2[kt], ah);
#pragma unroll
            for (int r = 0; r < 4; ++r) {
                const float h = tanh_f(ah[r]);
                y_reg[r] = (1.0f - zf[r]) * h + zf[r] * yode[r];
                const int row = (lane >> 4) * 4 + r;
                *(short*)(smem + OFF_Y + row * RB_Y + n2 * 2) = f2bf(y_reg[r]);
            }
            if (lane < 32) {
#pragma unroll
                for (int r = 0; r < 4; ++r) {
                    const int row = (lane >> 4) * 4 + r;  // 0..7
                    out_ys[((size_t)(b0 + row) * (TSTEP - 1) + s) * 64 + n2] =
                        y_reg[r];
                }
                if (s == TSTEP - 2) {
#pragma unroll
                    for (int r = 0; r < 4; ++r) {
                        const int row = (lane >> 4) * 4 + r;
                        out_yi[(size_t)(b0 + row) * 64 + n2] = y_reg[r];
                    }
                }
            }
        }
        __syncthreads();
    }
}

extern "C" void kernel_launch(void* const* d_in, const int* in_sizes, int n_in,
                              void* d_out, int out_size, void* d_ws, size_t ws_size,
                              hipStream_t stream) {
    const float* data = (const float*)d_in[0];
    const float* tsv  = (const float*)d_in[1];
    const float* Wf1 = (const float*)d_in[2];  const float* bf1 = (const float*)d_in[3];
    const float* Wf2 = (const float*)d_in[4];  const float* bf2 = (const float*)d_in[5];
    const float* Wz1 = (const float*)d_in[6];  const float* bz1 = (const float*)d_in[7];
    const float* Wz2 = (const float*)d_in[8];  const float* bz2 = (const float*)d_in[9];
    const float* Wr1 = (const float*)d_in[10]; const float* br1 = (const float*)d_in[11];
    const float* Wr2 = (const float*)d_in[12]; const float* br2 = (const float*)d_in[13];
    const float* Wh1 = (const float*)d_in[14]; const float* bh1 = (const float*)d_in[15];
    const float* Wh2 = (const float*)d_in[16]; const float* bh2 = (const float*)d_in[17];

    float* out_yi = (float*)d_out;
    float* out_ys = out_yi + (size_t)NBT * 64;

    ode_rnn_mfma<<<NBT / NT, 256, 0, stream>>>(
        data, tsv, Wf1, bf1, Wf2, bf2, Wz1, bz1, Wz2, bz2,
        Wr1, br1, Wr2, br2, Wh1, bh1, Wh2, bh2, out_yi, out_ys);
}

// Round 5
// 355.462 us; speedup vs baseline: 14.9601x; 1.1827x over previous
//
#include <hip/hip_runtime.h>

// ODE-RNN via MFMA, 8-wave blocks for 2 waves/SIMD latency hiding.
// 256 blocks x 512 threads (8 waves); NT=8 trajs/block; weights in VGPRs as
// bf16 B-fragments; activations bf16 in LDS; GRU state fp32 in regs (waves 0-3).
// W1 layers (128 units padded): wave w owns N-tile w (8 tiles).
// W2 layers (64 out = 4 tiles): f2/z2/h2 on waves 0-3 (tile w, carry state);
// r2 on waves 4-7 (tile w-4), which also build ch = yode*r in-place in c.
// Fragment mapping (16x16x32 bf16): A: lane l -> A[l&15][kt*32+(l>>4)*8+j],
// B: lane l -> B[kt*32+(l>>4)*8+j][l&15], C/D: col=l&15, row=(l>>4)*4+reg.

#define NBT   2048
#define TSTEP 200
#define NT    8

typedef short s8v __attribute__((ext_vector_type(8)));   // 8 bf16 (4 VGPRs)
typedef float f4v __attribute__((ext_vector_type(4)));

// LDS: bf16 tiles, row pitch with (pitch/4)%32==4 -> 2-way worst (free), 16B aligned
#define RB_Y 144   // y  [16][64]  bf16 (+pad)
#define RB_C 272   // c  [16][128] bf16 (+pad); also pitch for h buffers
#define OFF_Y  0
#define OFF_C  2304
#define OFF_HF 6656
#define OFF_HZ 11008
#define OFF_HR 15360
#define OFF_HH 19712
#define SMEM_TOT 24064

__device__ __forceinline__ unsigned cvtpk(float lo, float hi) {
    unsigned r;
    asm("v_cvt_pk_bf16_f32 %0, %1, %2" : "=v"(r) : "v"(lo), "v"(hi));
    return r;
}
__device__ __forceinline__ unsigned short f2bf(float f) {  // staging only
    unsigned int b = __float_as_uint(f);
    return (unsigned short)((b + 0x7fffu + ((b >> 16) & 1u)) >> 16);
}
__device__ __forceinline__ float bf2f(unsigned short u) {
    return __uint_as_float(((unsigned)u) << 16);
}
__device__ __forceinline__ float tanh_f(float x) {
    float e = __expf(2.0f * x);
    return fmaf(-2.0f, __builtin_amdgcn_rcpf(e + 1.0f), 1.0f);
}
__device__ __forceinline__ float sigm_f(float x) {
    return __builtin_amdgcn_rcpf(1.0f + __expf(-x));
}
__device__ __forceinline__ f4v mfma16(s8v a, s8v b, f4v c) {
    return __builtin_amdgcn_mfma_f32_16x16x32_bf16(a, b, c, 0, 0, 0);
}
__device__ __forceinline__ f4v splat(float b) { f4v v = {b, b, b, b}; return v; }

// B-fragment: lane holds W[k0+j][n] j=0..7, bf16 (zero-padded outside)
__device__ __forceinline__ s8v load_bfrag(const float* __restrict__ W,
                                          int Ncols, int Krows, int k0, int n) {
    s8v r;
#pragma unroll
    for (int j = 0; j < 8; ++j) {
        const int k = k0 + j;
        const float v = (k < Krows && n < Ncols) ? W[k * Ncols + n] : 0.0f;
        r[j] = (short)f2bf(v);
    }
    return r;
}

// A-fragment: lane l -> act[l&15][kt*32+(l>>4)*8 .. +7]; row byte off kt*64+(l>>4)*16
template <int RB>
__device__ __forceinline__ s8v load_af(const char* base, int lane, int kt) {
    return *(const s8v*)(base + (lane & 15) * RB + ((lane >> 4) * 16) + kt * 64);
}

// write 4 fp32 values (rows rb..rb+3, one col) as bf16 via cvt_pk
__device__ __forceinline__ void store4(char* base, int col2, int rb, int pitch,
                                       float v0, float v1, float v2, float v3) {
    const unsigned u01 = cvtpk(v0, v1), u23 = cvtpk(v2, v3);
    *(short*)(base + (rb + 0) * pitch + col2) = (short)(u01 & 0xffffu);
    *(short*)(base + (rb + 1) * pitch + col2) = (short)(u01 >> 16);
    *(short*)(base + (rb + 2) * pitch + col2) = (short)(u23 & 0xffffu);
    *(short*)(base + (rb + 3) * pitch + col2) = (short)(u23 >> 16);
}
__device__ __forceinline__ void store_tanh(char* base, int n0, int lane, f4v a) {
    store4(base, (n0 + (lane & 15)) * 2, (lane >> 4) * 4, RB_C,
           tanh_f(a[0]), tanh_f(a[1]), tanh_f(a[2]), tanh_f(a[3]));
}

__global__ __launch_bounds__(512, 2) void ode_rnn_mfma8(
    const float* __restrict__ data, const float* __restrict__ tsv,
    const float* __restrict__ Wf1, const float* __restrict__ bf1,
    const float* __restrict__ Wf2, const float* __restrict__ bf2,
    const float* __restrict__ Wz1, const float* __restrict__ bz1,
    const float* __restrict__ Wz2, const float* __restrict__ bz2,
    const float* __restrict__ Wr1, const float* __restrict__ br1,
    const float* __restrict__ Wr2, const float* __restrict__ br2,
    const float* __restrict__ Wh1, const float* __restrict__ bh1,
    const float* __restrict__ Wh2, const float* __restrict__ bh2,
    float* __restrict__ out_yi, float* __restrict__ out_ys)
{
    __shared__ __align__(16) char smem[SMEM_TOT];

    const int tid  = threadIdx.x;
    const int lane = tid & 63;
    const int wv   = tid >> 6;          // 0..7
    const bool isA = (wv < 4);          // state-carrying waves
    const int b0   = blockIdx.x * NT;

    for (int i = tid; i < SMEM_TOT / 4; i += 512) ((unsigned*)smem)[i] = 0u;

    // ---- stage weight B-fragments ----
    const int kb = (lane >> 4) * 8;
    const int n1 = wv * 16 + (lane & 15);          // W1 tile wv (cols 0..127)
    const int n2 = (wv & 3) * 16 + (lane & 15);    // W2 tile (cols 0..63)

    s8v Bf1[2], Bz1[4], Br1[4], Bh1[4];
    s8v Bf2[4], Bz2[4], Bh2[4], Br2[4];
#pragma unroll
    for (int kt = 0; kt < 2; ++kt)
        Bf1[kt] = load_bfrag(Wf1, 100, 64, kt * 32 + kb, n1);
#pragma unroll
    for (int kt = 0; kt < 4; ++kt) {
        Bz1[kt] = load_bfrag(Wz1, 100, 128, kt * 32 + kb, n1);
        Br1[kt] = load_bfrag(Wr1, 100, 128, kt * 32 + kb, n1);
        Bh1[kt] = load_bfrag(Wh1, 100, 128, kt * 32 + kb, n1);
    }
    if (isA) {
#pragma unroll
        for (int kt = 0; kt < 4; ++kt) {
            Bf2[kt] = load_bfrag(Wf2, 64, 100, kt * 32 + kb, n2);
            Bz2[kt] = load_bfrag(Wz2, 64, 100, kt * 32 + kb, n2);
            Bh2[kt] = load_bfrag(Wh2, 64, 100, kt * 32 + kb, n2);
        }
    } else {
#pragma unroll
        for (int kt = 0; kt < 4; ++kt)
            Br2[kt] = load_bfrag(Wr2, 64, 100, kt * 32 + kb, n2);
    }

    const float b1f = (n1 < 100) ? bf1[n1] : 0.0f;
    const float b1z = (n1 < 100) ? bz1[n1] : 0.0f;
    const float b1r = (n1 < 100) ? br1[n1] : 0.0f;
    const float b1h = (n1 < 100) ? bh1[n1] : 0.0f;
    const float bF2 = isA ? bf2[n2] : 0.0f;
    const float bZ2 = isA ? bz2[n2] : 0.0f;
    const float bH2 = isA ? bh2[n2] : 0.0f;
    const float bR2 = isA ? 0.0f : br2[n2];

    // x staging (waves 4-7): thread -> (traj, 2 elems)
    const int t2  = tid & 255;
    const int xtr = t2 >> 5;
    const int xd  = (t2 & 31) * 2;

    const int col2 = n2 * 2;            // byte col for W2-output writes
    const int rb   = (lane >> 4) * 4;   // C/D row base

    f4v y_reg = splat(0.0f), yode = splat(0.0f), zf = splat(0.0f);
    __syncthreads();

    for (int s = 0; s < TSTEP - 1; ++s) {
        float2 xv;
        if (!isA)
            xv = *(const float2*)&data[((size_t)(b0 + xtr) * TSTEP + (s + 1)) * 64 + xd];
        const float dt = (s == 0) ? (tsv[1] - tsv[0]) : (tsv[s - 1] - tsv[s]);

        // ---- P1: f1 hidden (all waves, tile wv) ----
        {
            const s8v ya0 = load_af<RB_Y>(smem + OFF_Y, lane, 0);
            const s8v ya1 = load_af<RB_Y>(smem + OFF_Y, lane, 1);
            f4v a = splat(b1f);
            a = mfma16(ya0, Bf1[0], a);
            a = mfma16(ya1, Bf1[1], a);
            store_tanh(smem + OFF_HF, wv * 16, lane, a);
        }
        __syncthreads();

        // ---- P2: f2 out (w0-3) -> yode -> c[:, :64]; x -> c[:, 64:] (w4-7) ----
        if (isA) {
            f4v ac = splat(bF2);
#pragma unroll
            for (int kt = 0; kt < 4; ++kt)
                ac = mfma16(load_af<RB_C>(smem + OFF_HF, lane, kt), Bf2[kt], ac);
#pragma unroll
            for (int r = 0; r < 4; ++r) yode[r] = fmaf(dt, ac[r], y_reg[r]);
            store4(smem + OFF_C, col2, rb, RB_C, yode[0], yode[1], yode[2], yode[3]);
        } else {
            *(unsigned*)(smem + OFF_C + xtr * RB_C + 128 + (t2 & 31) * 4) =
                cvtpk(xv.x, xv.y);
        }
        __syncthreads();

        // ---- P3: z1 + r1 hidden (all waves, tile wv) ----
        {
            const s8v c0 = load_af<RB_C>(smem + OFF_C, lane, 0);
            const s8v c1 = load_af<RB_C>(smem + OFF_C, lane, 1);
            const s8v c2 = load_af<RB_C>(smem + OFF_C, lane, 2);
            const s8v c3 = load_af<RB_C>(smem + OFF_C, lane, 3);
            f4v az = splat(b1z), ar = splat(b1r);
            az = mfma16(c0, Bz1[0], az); az = mfma16(c1, Bz1[1], az);
            az = mfma16(c2, Bz1[2], az); az = mfma16(c3, Bz1[3], az);
            ar = mfma16(c0, Br1[0], ar); ar = mfma16(c1, Br1[1], ar);
            ar = mfma16(c2, Br1[2], ar); ar = mfma16(c3, Br1[3], ar);
            store_tanh(smem + OFF_HZ, wv * 16, lane, az);
            store_tanh(smem + OFF_HR, wv * 16, lane, ar);
        }
        __syncthreads();

        // ---- P4: z2 (w0-3, zf in regs) | r2 (w4-7) + ch=yode*r in-place ----
        if (isA) {
            f4v az = splat(bZ2);
#pragma unroll
            for (int kt = 0; kt < 4; ++kt)
                az = mfma16(load_af<RB_C>(smem + OFF_HZ, lane, kt), Bz2[kt], az);
#pragma unroll
            for (int r = 0; r < 4; ++r) zf[r] = sigm_f(az[r]);
        } else {
            f4v ar = splat(bR2);
#pragma unroll
            for (int kt = 0; kt < 4; ++kt)
                ar = mfma16(load_af<RB_C>(smem + OFF_HR, lane, kt), Br2[kt], ar);
            float ch[4];
#pragma unroll
            for (int r = 0; r < 4; ++r) {
                const unsigned short yv =
                    *(const unsigned short*)(smem + OFF_C + (rb + r) * RB_C + col2);
                ch[r] = bf2f(yv) * sigm_f(ar[r]);
            }
            store4(smem + OFF_C, col2, rb, RB_C, ch[0], ch[1], ch[2], ch[3]);
        }
        __syncthreads();

        // ---- P5: h1 hidden (all waves, tile wv) ----
        {
            const s8v d0 = load_af<RB_C>(smem + OFF_C, lane, 0);
            const s8v d1 = load_af<RB_C>(smem + OFF_C, lane, 1);
            const s8v d2 = load_af<RB_C>(smem + OFF_C, lane, 2);
            const s8v d3 = load_af<RB_C>(smem + OFF_C, lane, 3);
            f4v ah = splat(b1h);
            ah = mfma16(d0, Bh1[0], ah); ah = mfma16(d1, Bh1[1], ah);
            ah = mfma16(d2, Bh1[2], ah); ah = mfma16(d3, Bh1[3], ah);
            store_tanh(smem + OFF_HH, wv * 16, lane, ah);
        }
        __syncthreads();

        // ---- P6: h2 out (w0-3); y = (1-z)*h + z*yode; LDS + global ----
        if (isA) {
            f4v ah = splat(bH2);
#pragma unroll
            for (int kt = 0; kt < 4; ++kt)
                ah = mfma16(load_af<RB_C>(smem + OFF_HH, lane, kt), Bh2[kt], ah);
#pragma unroll
            for (int r = 0; r < 4; ++r) {
                const float h = tanh_f(ah[r]);
                y_reg[r] = (1.0f - zf[r]) * h + zf[r] * yode[r];
            }
            store4(smem + OFF_Y, col2, rb, RB_Y, y_reg[0], y_reg[1], y_reg[2], y_reg[3]);
            if (lane < 32) {
#pragma unroll
                for (int r = 0; r < 4; ++r) {
                    const int row = rb + r;  // 0..7
                    out_ys[((size_t)(b0 + row) * (TSTEP - 1) + s) * 64 + n2] = y_reg[r];
                }
                if (s == TSTEP - 2) {
#pragma unroll
                    for (int r = 0; r < 4; ++r)
                        out_yi[(size_t)(b0 + rb + r) * 64 + n2] = y_reg[r];
                }
            }
        }
        __syncthreads();
    }
}

extern "C" void kernel_launch(void* const* d_in, const int* in_sizes, int n_in,
                              void* d_out, int out_size, void* d_ws, size_t ws_size,
                              hipStream_t stream) {
    const float* data = (const float*)d_in[0];
    const float* tsv  = (const float*)d_in[1];
    const float* Wf1 = (const float*)d_in[2];  const float* bf1 = (const float*)d_in[3];
    const float* Wf2 = (const float*)d_in[4];  const float* bf2 = (const float*)d_in[5];
    const float* Wz1 = (const float*)d_in[6];  const float* bz1 = (const float*)d_in[7];
    const float* Wz2 = (const float*)d_in[8];  const float* bz2 = (const float*)d_in[9];
    const float* Wr1 = (const float*)d_in[10]; const float* br1 = (const float*)d_in[11];
    const float* Wr2 = (const float*)d_in[12]; const float* br2 = (const float*)d_in[13];
    const float* Wh1 = (const float*)d_in[14]; const float* bh1 = (const float*)d_in[15];
    const float* Wh2 = (const float*)d_in[16]; const float* bh2 = (const float*)d_in[17];

    float* out_yi = (float*)d_out;
    float* out_ys = out_yi + (size_t)NBT * 64;

    ode_rnn_mfma8<<<NBT / NT, 512, 0, stream>>>(
        data, tsv, Wf1, bf1, Wf2, bf2, Wz1, bz1, Wz2, bz2,
        Wr1, br1, Wr2, br2, Wh1, bh1, Wh2, bh2, out_yi, out_ys);
}